// Round 3
// baseline (92.400 us; speedup 1.0000x reference)
//
#include <hip/hip_runtime.h>

// EvalEig round 3: 32-segment transfer-matrix decomposition of the 894-step
// inward recurrence, 512-thread blocks (16 chains x 32 segs) -> 6144 waves,
// 40 KB LDS -> 4 blocks/CU (~26 waves/CU) for latency hiding (round 2 was
// 3 waves/SIMD and still latency-bound at ~31 us vs ~8 us issue-bound).
// Raw v_rcp_f32 (no NR, ~1ulp; error margin 4.3x) cuts 4 fma/step and
// shortens dep chains. Nontemporal stores for the 48 MB streamed u-arrays.

namespace {
constexpr int kNE    = 4096;
constexpr int kNCH   = kNE * 3;        // 12288 chains
constexpr int kMatch = 100;
constexpr float kC   = 3.0f / 40.0f * 0.01f;
constexpr float kK1  = 13.0f / 15.0f * 0.01f;
constexpr float kK2  = 7.0f / 60.0f * 0.01f;
constexpr int kSeg        = 32;
constexpr int kCPB        = 16;           // chains per block
constexpr int kZeroBlocks = kNCH / 512;   // 24
constexpr int kInfBlocks  = kNCH / kCPB;  // 768
}

__device__ __forceinline__ float rcp_f(float x) { return __builtin_amdgcn_rcpf(x); }
__device__ __forceinline__ void nt_store(float v, float* p) { __builtin_nontemporal_store(v, p); }

__global__ __launch_bounds__(512) void solve_kernel(const float* __restrict__ energy,
                                                    float* __restrict__ out,
                                                    float* __restrict__ ws)
{
    __shared__ float sP[kSeg][kCPB][16];   // 32 KB (reused as sR4/sR2 after phase 2)
    __shared__ float sSt[kSeg][kCPB][4];   // 8 KB
    float* sR4 = &sP[0][0][0];
    float* sR2 = sR4 + kSeg * kCPB;

    const int bid = (int)blockIdx.x;
    const int tid = (int)threadIdx.x;
    float* uzero = out + kNCH;
    float* uinf  = out + kNCH + (size_t)kMatch * kNCH;

    if (bid < kZeroBlocks) {
        // ---------------- u_zero: outward solve, 94 steps, 1 thread/chain ----
        const int t  = bid * 512 + tid;
        const int l  = t % 3;
        const int ei = t / 3;
        const float e = energy[ei], negE = -e;
        const float ll1 = (float)(l * (l + 1));
        const float rdiv = (l == 0) ? 0.5f : ((l == 1) ? 0.25f : (1.0f/6.0f));
        float p0,p1,p2,p3,p4;
        {
            float pw[5];
            #pragma unroll
            for (int k = 0; k < 5; ++k) {
                float r = 0.1f * (float)(k + 1);
                float rl1 = (l == 0) ? r : ((l == 1) ? r*r : r*r*r);
                pw[k] = rl1 - (rl1 * r) * rdiv;
                nt_store(pw[k], uzero + (size_t)k * kNCH + t);
            }
            nt_store(pw[4], uzero + (size_t)5 * kNCH + t);
            p0=pw[0]; p1=pw[1]; p2=pw[2]; p3=pw[3]; p4=pw[4];
        }
        float acc4, acc2;
        {
            float q0=p0*p0, q1=p1*p1, q2=p2*p2, q3=p3*p3, q4=p4*p4;
            acc4 = 7.0f*q0*q0 + 32.0f*q1*q1 + 32.0f*q3*q3 + 14.0f*q4*q4 + 32.0f*q4*q4;
            acc2 = q2;
        }
        float f0, f1, f2, f3;
        {
            float i1 = rcp_f(0.2f), i2 = rcp_f(0.3f), i3 = rcp_f(0.4f), i4 = rcp_f(0.5f);
            f0 = fmaf(i1, fmaf(ll1, i1, -1.0f), negE);
            f1 = fmaf(i2, fmaf(ll1, i2, -1.0f), negE);
            f2 = fmaf(i3, fmaf(ll1, i3, -1.0f), negE);
            f3 = fmaf(i4, fmaf(ll1, i4, -1.0f), negE);
        }
        float* ptr = uzero + (size_t)6 * kNCH + t;
        #pragma unroll 4
        for (int j = 5; j <= 98; ++j) {
            float ri = rcp_f(fmaf((float)j, 0.1f, 0.1f));
            float f4 = fmaf(ri, fmaf(ll1, ri, -1.0f), negE);
            float iv = rcp_f(fmaf(-kC, f4, 1.0f));
            float a  = fmaf(kC  * f0, iv, -1.0f);
            float b  = fmaf(kK1 * f1, iv,  2.0f);
            float cc = fmaf(kK2 * f2, iv, -2.0f);
            float d  = fmaf(kK1 * f3, iv,  2.0f);
            float nw = fmaf(d, p4, fmaf(cc, p3, fmaf(b, p2, a * p1)));
            nt_store(nw, ptr); ptr += kNCH;
            float v2 = nw*nw, v4 = v2*v2;
            if (j <= 94) {
                int m = (j + 1) & 3;
                if (m == 2)      acc2 += v2;
                else if (m == 0) acc4 += 14.0f * v4;
                else             acc4 += 32.0f * v4;
            } else if (j == 95) {
                acc4 += 7.0f * v4;
            }
            f0 = f1; f1 = f2; f2 = f3; f3 = f4;
            p0 = p1; p1 = p2; p2 = p3; p3 = p4; p4 = nw;
        }
        float integ = fmaf(12.0f, acc2, acc4) * (2.0f * 0.1f / 45.0f);
        float deriv = fmaf(25.0f, p4, fmaf(-48.0f, p3, fmaf(36.0f, p2,
                      fmaf(-16.0f, p1, 3.0f * p0)))) * (1.0f / 1.2f);
        ws[2 * kNCH + t] = deriv / p4;
        ws[3 * kNCH + t] = integ / (p4 * p4);
        return;
    }

    // ---------------- u_infty: 32-segment inward solve ----------------
    const int b = bid - kZeroBlocks;
    const int g = tid & 15;            // chain within block
    const int s = tid >> 4;            // segment 0..31
    const int t = b * kCPB + g;
    const int l  = t % 3;
    const int ei = t / 3;
    const float e = energy[ei], negE = -e;
    const float ll1 = (float)(l * (l + 1));
    const int jstart = 5 + 28 * s;     // seg s: 28 steps (26 for s=31)
    int j = jstart;

    float F0, F1, F2, F3;
    {
        float i0 = rcp_f(fmaf((float)(jstart - 4), -0.1f, 100.0f));
        float i1 = rcp_f(fmaf((float)(jstart - 3), -0.1f, 100.0f));
        float i2 = rcp_f(fmaf((float)(jstart - 2), -0.1f, 100.0f));
        float i3 = rcp_f(fmaf((float)(jstart - 1), -0.1f, 100.0f));
        F0 = fmaf(i0, fmaf(ll1, i0, -1.0f), negE);
        F1 = fmaf(i1, fmaf(ll1, i1, -1.0f), negE);
        F2 = fmaf(i2, fmaf(ll1, i2, -1.0f), negE);
        F3 = fmaf(i3, fmaf(ll1, i3, -1.0f), negE);
    }
    const float ff0 = F0, ff1 = F1, ff2 = F2, ff3 = F3;

    float ca, cb, cc_, cd;
#define COEF(FA,FB,FC,FD) \
    { float ri = rcp_f(fmaf((float)j, -0.1f, 100.0f)); \
      float f4 = fmaf(ri, fmaf(ll1, ri, -1.0f), negE); \
      float iv = rcp_f(fmaf(-kC, f4, 1.0f)); \
      ca  = fmaf(kC  * FA, iv, -1.0f); \
      cb  = fmaf(kK1 * FB, iv,  2.0f); \
      cc_ = fmaf(kK2 * FC, iv, -2.0f); \
      cd  = fmaf(kK1 * FD, iv,  2.0f); \
      FA = f4; }

#define MSTEP(FA,FB,FC,FD,RA,RB,RC,RD) \
    { COEF(FA,FB,FC,FD) \
      RA[0] = fmaf(cd,RD[0], fmaf(cc_,RC[0], fmaf(cb,RB[0], ca*RA[0]))); \
      RA[1] = fmaf(cd,RD[1], fmaf(cc_,RC[1], fmaf(cb,RB[1], ca*RA[1]))); \
      RA[2] = fmaf(cd,RD[2], fmaf(cc_,RC[2], fmaf(cb,RB[2], ca*RA[2]))); \
      RA[3] = fmaf(cd,RD[3], fmaf(cc_,RC[3], fmaf(cb,RB[3], ca*RA[3]))); \
      ++j; }

    // ---- phase 1: per-segment 4x4 companion product (seg 31's matrix unused)
    if (s < kSeg - 1) {
        float ra[4] = {1,0,0,0}, rb[4] = {0,1,0,0}, rc[4] = {0,0,1,0}, rd[4] = {0,0,0,1};
        for (int it = 0; it < 7; ++it) {   // 28 steps, rotation restored
            MSTEP(F0,F1,F2,F3, ra,rb,rc,rd)
            MSTEP(F1,F2,F3,F0, rb,rc,rd,ra)
            MSTEP(F2,F3,F0,F1, rc,rd,ra,rb)
            MSTEP(F3,F0,F1,F2, rd,ra,rb,rc)
        }
        float* dst = &sP[s][g][0];
        #pragma unroll
        for (int c = 0; c < 4; ++c) {
            dst[c] = ra[c]; dst[4+c] = rb[c]; dst[8+c] = rc[c]; dst[12+c] = rd[c];
        }
    }
    __syncthreads();

    // ---- phase 2: per-chain serial combine (lanes with s==0)
    if (s == 0) {
        const float se  = sqrtf(fabsf(e));
        const float rfc = (l == 0) ? 1.0f : ((l == 1) ? (1.0f/3.0f) : (1.0f/15.0f));
        const float rt1 = (l == 0) ? (1.0f/3.0f) : ((l == 1) ? (1.0f/5.0f) : (1.0f/7.0f));
        const float rt2 = (l == 0) ? (1.0f/30.0f) : ((l == 1) ? (1.0f/70.0f) : (1.0f/126.0f));
        float pw[5];
        #pragma unroll
        for (int k = 0; k < 5; ++k) {
            float rinf = 99.6f + 0.1f * (float)k;
            float x  = rinf * se;
            float xl = (l == 0) ? 1.0f : ((l == 1) ? x : x * x);
            float h  = x * x * 0.5f;
            pw[k] = rinf * (xl * rfc * (1.0f + h * rt1 + (h * h) * rt2));
        }
        nt_store(pw[4], uinf + (size_t)899 * kNCH + t);
        float st0 = pw[1], st1 = pw[2], st2 = pw[3], st3 = pw[4];
        for (int ss = 0; ss < kSeg; ++ss) {
            sSt[ss][g][0] = st0; sSt[ss][g][1] = st1;
            sSt[ss][g][2] = st2; sSt[ss][g][3] = st3;
            if (ss < kSeg - 1) {
                const float* P = &sP[ss][g][0];
                float n0 = fmaf(P[ 3],st3, fmaf(P[ 2],st2, fmaf(P[ 1],st1, P[ 0]*st0)));
                float n1 = fmaf(P[ 7],st3, fmaf(P[ 6],st2, fmaf(P[ 5],st1, P[ 4]*st0)));
                float n2 = fmaf(P[11],st3, fmaf(P[10],st2, fmaf(P[ 9],st1, P[ 8]*st0)));
                float n3 = fmaf(P[15],st3, fmaf(P[14],st2, fmaf(P[13],st1, P[12]*st0)));
                st0 = n0; st1 = n1; st2 = n2; st3 = n3;
            }
        }
    }
    __syncthreads();

    // ---- phase 3: replay from exact segment-initial state
    j = jstart;
    F0 = ff0; F1 = ff1; F2 = ff2; F3 = ff3;
    float p0 = sSt[s][g][0], p1 = sSt[s][g][1], p2 = sSt[s][g][2], p3 = sSt[s][g][3];
    float acc4 = 0.0f, acc2 = 0.0f;
    float* ptr = uinf + (size_t)(903 - jstart) * kNCH + t;
#define RSTEP(FA,FB,FC,FD,PA,PB,PC,PD) \
    { COEF(FA,FB,FC,FD) \
      float nw = fmaf(cd,PD, fmaf(cc_,PC, fmaf(cb,PB, ca*PA))); \
      PA = nw; nt_store(nw, ptr); ptr -= kNCH; \
      float v2 = nw*nw, v4 = v2*v2; \
      if (j >= 8) { int m = j & 3; \
        if (m == 1) acc2 += v2; \
        else acc4 += ((m == 3) ? 14.0f : 32.0f) * v4; } \
      else if (j == 7) acc4 += 7.0f * v4; \
      ++j; }

    float h0 = 0.0f;
    if (s < kSeg - 1) {
        for (int it = 0; it < 7; ++it) {   // 28 steps
            RSTEP(F0,F1,F2,F3, p0,p1,p2,p3)
            RSTEP(F1,F2,F3,F0, p1,p2,p3,p0)
            RSTEP(F2,F3,F0,F1, p2,p3,p0,p1)
            RSTEP(F3,F0,F1,F2, p3,p0,p1,p2)
        }
    } else {
        for (int it = 0; it < 6; ++it) {   // 24 steps
            RSTEP(F0,F1,F2,F3, p0,p1,p2,p3)
            RSTEP(F1,F2,F3,F0, p1,p2,p3,p0)
            RSTEP(F2,F3,F0,F1, p2,p3,p0,p1)
            RSTEP(F3,F0,F1,F2, p3,p0,p1,p2)
        }
        // window: p0=w893, p1=w894, p2=w895, p3=w896
        RSTEP(F0,F1,F2,F3, p0,p1,p2,p3)    // j=897 -> p0=w897
        h0 = p1;                            // w894, about to be overwritten
        RSTEP(F1,F2,F3,F0, p1,p2,p3,p0)    // j=898 -> p1=w898
        // h-window: h0=w894, p2=w895, p3=w896, p0=w897, p1=w898
    }
    sR4[s * kCPB + g] = acc4;   // aliases sP (done with it after phase 2)
    sR2[s * kCPB + g] = acc2;
    __syncthreads();

    if (s == kSeg - 1) {
        float a4 = 0.0f, a2 = 0.0f;
        #pragma unroll
        for (int ss = 0; ss < kSeg; ++ss) {
            a4 += sR4[ss * kCPB + g]; a2 += sR2[ss * kCPB + g];
        }
        float h1 = p2, h2 = p3, h3 = p0, h4 = p1;
        nt_store(h0, uinf + (size_t)0 * kNCH + t);
        nt_store(h1, uinf + (size_t)1 * kNCH + t);
        nt_store(h2, uinf + (size_t)2 * kNCH + t);
        nt_store(h3, uinf + (size_t)3 * kNCH + t);
        nt_store(h4, uinf + (size_t)4 * kNCH + t);
        float q0 = h0*h0, q1 = h1*h1, q2 = h2*h2, q3 = h3*h3, q4 = h4*h4;
        a4 += 7.0f*q0*q0 + 32.0f*q1*q1 + 32.0f*q3*q3 + 14.0f*q4*q4;
        a2 += q2;
        float integ = fmaf(12.0f, a2, a4) * (2.0f * 0.1f / 45.0f);
        float deriv = fmaf(25.0f, h0, fmaf(-48.0f, h1, fmaf(36.0f, h2,
                      fmaf(-16.0f, h3, 3.0f * h4)))) * (1.0f / 1.2f);
        ws[t]        = deriv / h0;            // lfunc_out (pre energy-reversal)
        ws[kNCH + t] = integ / (h0 * h0);     // integ_out / u_infty[0]^2
    }
#undef RSTEP
#undef MSTEP
#undef COEF
}

__global__ __launch_bounds__(256) void final_kernel(const float* __restrict__ energy,
                                                    const float* __restrict__ ws,
                                                    float* __restrict__ out)
{
    int t = (int)blockIdx.x * 256 + (int)threadIdx.x;
    if (t >= kNCH) return;
    int l = t % 3, ei = t / 3;
    float lf_out = ws[(kNE - 1 - ei) * 3 + l];   // energy-axis reversed
    float lf_in  = ws[2 * kNCH + t];
    float den    = ws[kNCH + t] + ws[3 * kNCH + t];
    out[t] = energy[ei] - (lf_out - lf_in) / den;
}

extern "C" void kernel_launch(void* const* d_in, const int* in_sizes, int n_in,
                              void* d_out, int out_size, void* d_ws, size_t ws_size,
                              hipStream_t stream) {
    (void)in_sizes; (void)n_in; (void)out_size; (void)ws_size;
    const float* energy = (const float*)d_in[0];
    float* out = (float*)d_out;
    float* ws  = (float*)d_ws;   // 4*12288 floats = 192 KB scratch
    solve_kernel<<<kZeroBlocks + kInfBlocks, 512, 0, stream>>>(energy, out, ws);
    final_kernel<<<kNCH / 256, 256, 0, stream>>>(energy, ws, out);
}